// Round 22
// baseline (460.628 us; speedup 1.0000x reference)
//
#include <hip/hip_runtime.h>
#include <hip/hip_bf16.h>

#define S_  512
#define F_  64
#define H_  32
#define GQ  128   // 4*H
#define BT  4     // real batch rows per block
#define NB  512   // 2048/BT -> two blocks per CU

#define HS  40    // h plane row stride (ushorts)
#define GS  33    // head buffer row stride (floats)

#define L2E 1.4426950408889634f          // log2(e)
#define CN2 (-2.8853900817779268f)       // -2*log2(e)

typedef __attribute__((ext_vector_type(8))) short bf16x8;
typedef __attribute__((ext_vector_type(4))) float f32x4;

// f32 -> bf16 via HW cvt (RNE)
__device__ __forceinline__ unsigned short bf16s(float f) {
    return __builtin_bit_cast(unsigned short, __float2bfloat16(f));
}
// 2x f32 -> packed bf16x2 (compiler fuses pair casts to v_cvt_pk_bf16_f32)
__device__ __forceinline__ unsigned bf16pk(float x, float y) {
    return (unsigned)bf16s(x) | ((unsigned)bf16s(y) << 16);
}
// 8 floats (two float4) -> bf16x8 fragment
__device__ __forceinline__ bf16x8 mk8(float4 p, float4 q) {
    uint4 t = { bf16pk(p.x, p.y), bf16pk(p.z, p.w),
                bf16pk(q.x, q.y), bf16pk(q.z, q.w) };
    return __builtin_bit_cast(bf16x8, t);
}
// sigmoid with z pre-scaled by log2(e)
__device__ __forceinline__ float sigm2(float z) {
    return __builtin_amdgcn_rcpf(1.0f + __builtin_amdgcn_exp2f(-z));
}
// tanh(c), c linear domain
__device__ __forceinline__ float tanh2(float c) {
    return 2.0f * __builtin_amdgcn_rcpf(1.0f + __builtin_amdgcn_exp2f(c * CN2)) - 1.0f;
}

#define MFMA(A, B, C) __builtin_amdgcn_mfma_f32_16x16x32_bf16(A, B, C, 0, 0, 0)

// 8 waves, BT=4, TWO blocks per CU. Transposed MFMA, time-packed
// (col = batch(0..3) + 8*dt; rows 4..7/12..15 bounded garbage).
// R22: x comes straight from global per-lane (no x-LDS, no stagers) -> LDS
// carries ONLY h; per-block LDS port load ~36 cyc/wave/DSTEP, so two
// phase-independent blocks co-schedule on each CU and fill each other's
// latency stalls. Weights exp2-domain bf16; xz ping-pong; split XGEMM.
__global__ __launch_bounds__(512, 2)
void lstm_mfma_kernel(const float* __restrict__ x,  const float* __restrict__ Wx,
                      const float* __restrict__ Wh, const float* __restrict__ bg,
                      const float* __restrict__ W1, const float* __restrict__ b1,
                      const float* __restrict__ W2, const float* __restrict__ b2,
                      const float* __restrict__ Wo, const float* __restrict__ bo,
                      float* __restrict__ out)
{
    const int tid = threadIdx.x;     // 0..511
    const int w   = tid >> 6;        // wave id 0..7
    const int L   = tid & 63;
    const int c16 = L & 15;          // B col: batch + 8*dt / D col
    const int kg  = L >> 4;          // k-group AND unit-offset of D rows
    const int bb  = blockIdx.x * BT;
    const int jj  = (w << 2) + kg;   // hidden unit owned by this lane

    // A row m=c16 -> weight column; gate = c16&3; exp2-domain scale
    const int gcol = ((c16 & 3) << 5) + (w << 2) + (c16 >> 2);
    const float gsc = ((c16 & 3) == 2) ? (2.0f * L2E) : L2E;

    __shared__ __align__(16) unsigned short hh[2][16][HS];   // h hi-plane, parity
    __shared__ float Hd[3][BT][GS];

    // ---- register-resident weights (pure bf16, exp2-domain) ----
    bf16x8 whh_, wx0h, wx1h;
#pragma unroll
    for (int i = 0; i < 8; ++i) {
        wx0h[i] = (short)bf16s(Wx[(kg * 8 + i) * GQ + gcol] * gsc);
        wx1h[i] = (short)bf16s(Wx[(32 + kg * 8 + i) * GQ + gcol] * gsc);
        whh_[i] = (short)bf16s(Wh[(kg * 8 + i) * GQ + gcol] * gsc);
    }
    f32x4 biasC;
#pragma unroll
    for (int r = 0; r < 4; ++r)
        biasC[r] = bg[r * 32 + jj] * ((r == 2) ? (2.0f * L2E) : L2E);

    // ---- zero h planes (rows 8..15 stay zero forever) ----
    for (int i = tid; i < 2 * 16 * (HS / 2); i += 512)
        ((unsigned*)&hh[0][0][0])[i] = 0u;

    // ---- per-lane x source: batch row c16&3 (rows 4..7 alias -> in-bounds),
    //      dt bit folded into base; fragment features f0..f0+7 and 32+f0.. ----
    const int xbat = c16 & 3;
    const int xdt  = c16 >> 3;       // 0/1
    const float* xg = x + (size_t)(bb + xbat) * S_ * F_ + (size_t)xdt * F_;
    const int f0 = kg * 8;

    // prologue: slot 0 -> immediate frags; slot 1 -> A-set; slot 2 -> B-set
    float4 aL0 = *(const float4*)(xg + (size_t)2 * F_ + f0);
    float4 aL1 = *(const float4*)(xg + (size_t)2 * F_ + f0 + 4);
    float4 aH0 = *(const float4*)(xg + (size_t)2 * F_ + 32 + f0);
    float4 aH1 = *(const float4*)(xg + (size_t)2 * F_ + 32 + f0 + 4);
    float4 bL0 = *(const float4*)(xg + (size_t)4 * F_ + f0);
    float4 bL1 = *(const float4*)(xg + (size_t)4 * F_ + f0 + 4);
    float4 bH0 = *(const float4*)(xg + (size_t)4 * F_ + 32 + f0);
    float4 bH1 = *(const float4*)(xg + (size_t)4 * F_ + 32 + f0 + 4);

    f32x4 xzA, xz1A, xzB, xz1B;
    {
        float4 cL0 = *(const float4*)(xg + f0);
        float4 cL1 = *(const float4*)(xg + f0 + 4);
        float4 cH0 = *(const float4*)(xg + 32 + f0);
        float4 cH1 = *(const float4*)(xg + 32 + f0 + 4);
        bf16x8 bxh0 = mk8(cL0, cL1);
        bf16x8 bxh1 = mk8(cH0, cH1);
        f32x4 b0 = MFMA(wx0h, bxh0, biasC);
        xzA = MFMA(wx1h, bxh1, b0);
#pragma unroll
        for (int r = 0; r < 4; ++r) xz1A[r] = __shfl_xor(xzA[r], 8);
    }
    __syncthreads();   // h planes zeroed

    float cc = 0.0f;

#define DSTEP(TD, PL0, PL1, PH0, PH1, XZIN, XZ1IN, XZOUT, XZ1OUT) {            \
    const int td = (TD);                                                       \
    /* convert P (x slot td+1, loaded 2 DSTEPs ago) -> frags */                \
    bf16x8 bxh0 = mk8(PL0, PL1);                                               \
    bf16x8 bxh1 = mk8(PH0, PH1);                                               \
    /* reload P <- slot td+3 (consumed at DSTEP td+2) */                       \
    {                                                                          \
        int tl = td + 3; if (tl > 255) tl = 255;                               \
        const float* pg = xg + (size_t)(2 * tl) * F_;                          \
        PL0 = *(const float4*)(pg + f0);                                       \
        PL1 = *(const float4*)(pg + f0 + 4);                                   \
        PH0 = *(const float4*)(pg + 32 + f0);                                  \
        PH1 = *(const float4*)(pg + 32 + f0 + 4);                              \
    }                                                                          \
    /* phase 1: rec step 2td (h[2td-1] in plane 1) + XGEMM first half */       \
    bf16x8 bhh1 = *(const bf16x8*)&hh[1][c16][kg * 8];                         \
    f32x4 part = MFMA(wx0h, bxh0, biasC);                                      \
    f32x4 z = MFMA(whh_, bhh1, XZIN);                                          \
    float iv = sigm2(z[0]), fv = sigm2(z[1]);                                  \
    float gv = 2.0f * sigm2(z[2]) - 1.0f, ov = sigm2(z[3]);                    \
    cc = fmaf(fv, cc, iv * gv);                                                \
    float hv = ov * tanh2(cc);                                                 \
    if (c16 < 8) hh[0][c16][jj] = bf16s(hv);                                   \
    __syncthreads();   /* A: h[2td] visible */                                 \
    /* phase 2: rec step 2td+1 + XGEMM second half */                          \
    bf16x8 bhh0 = *(const bf16x8*)&hh[0][c16][kg * 8];                         \
    XZOUT = MFMA(wx1h, bxh1, part);                                            \
    _Pragma("unroll")                                                          \
    for (int r = 0; r < 4; ++r) XZ1OUT[r] = __shfl_xor(XZOUT[r], 8);           \
    z = MFMA(whh_, bhh0, XZ1IN);                                               \
    iv = sigm2(z[0]); fv = sigm2(z[1]);                                        \
    gv = 2.0f * sigm2(z[2]) - 1.0f; ov = sigm2(z[3]);                          \
    cc = fmaf(fv, cc, iv * gv);                                                \
    hv = ov * tanh2(cc);                                                       \
    if (c16 < 8) {                                                             \
        hh[1][c16][jj] = bf16s(hv);                                            \
        if (td == 255 && c16 < BT) Hd[0][c16][jj] = hv;                        \
    }                                                                          \
    __syncthreads();   /* B: h[2td+1] visible */                               \
}

    for (int qd = 0; qd < 128; ++qd) {
        DSTEP(2 * qd,     aL0, aL1, aH0, aH1, xzA, xz1A, xzB, xz1B)
        DSTEP(2 * qd + 1, bL0, bL1, bH0, bH1, xzB, xz1B, xzA, xz1A)
    }
#undef DSTEP

    __syncthreads();

    // ---- MLP head: 32 -> 32 -> 16 -> 3, leaky_relu(0.01) ----
    if (tid < BT * 32) {
        int rb = tid >> 5, n = tid & 31;
        float a = b1[n];
#pragma unroll
        for (int k = 0; k < 32; ++k) a = fmaf(Hd[0][rb][k], W1[k * 32 + n], a);
        a = (a > 0.0f) ? a : 0.01f * a;
        Hd[1][rb][n] = a;
    }
    __syncthreads();
    if (tid < BT * 16) {
        int rb = tid >> 4, n = tid & 15;
        float a = b2[n];
#pragma unroll
        for (int k = 0; k < 32; ++k) a = fmaf(Hd[1][rb][k], W2[k * 16 + n], a);
        a = (a > 0.0f) ? a : 0.01f * a;
        Hd[2][rb][n] = a;
    }
    __syncthreads();
    if (tid < BT * 3) {
        int rb = tid / 3, n = tid - rb * 3;
        float a = bo[n];
#pragma unroll
        for (int k = 0; k < 16; ++k) a = fmaf(Hd[2][rb][k], Wo[k * 3 + n], a);
        out[(size_t)(bb + rb) * 3 + n] = a;
    }
}

extern "C" void kernel_launch(void* const* d_in, const int* in_sizes, int n_in,
                              void* d_out, int out_size, void* d_ws, size_t ws_size,
                              hipStream_t stream) {
    const float* x  = (const float*)d_in[0];
    const float* Wx = (const float*)d_in[1];
    const float* Wh = (const float*)d_in[2];
    const float* bg = (const float*)d_in[3];
    const float* W1 = (const float*)d_in[4];
    const float* b1 = (const float*)d_in[5];
    const float* W2 = (const float*)d_in[6];
    const float* b2 = (const float*)d_in[7];
    const float* Wo = (const float*)d_in[8];
    const float* bo = (const float*)d_in[9];
    float* out = (float*)d_out;

    hipLaunchKernelGGL(lstm_mfma_kernel, dim3(NB), dim3(512), 0, stream,
                       x, Wx, Wh, bg, W1, b1, W2, b2, Wo, bo, out);
}

// Round 23
// 139.305 us; speedup vs baseline: 3.3066x; 3.3066x over previous
//
#include <hip/hip_runtime.h>
#include <hip/hip_bf16.h>

#define S_  512
#define F_  64
#define H_  32
#define GQ  128   // 4*H
#define BT  8     // real batch rows per block
#define NB  256   // 2048/BT -> one block per CU

#define XS  72    // x plane row stride (ushorts)
#define HS  40    // h plane row stride (ushorts)
#define GS  33    // head buffer row stride (floats)

#define L2E 1.4426950408889634f          // log2(e)
#define CN2 (-2.8853900817779268f)       // -2*log2(e)

typedef __attribute__((ext_vector_type(8))) short bf16x8;
typedef __attribute__((ext_vector_type(4))) float f32x4;

// f32 -> bf16 via HW cvt (RNE)
__device__ __forceinline__ unsigned short bf16s(float f) {
    return __builtin_bit_cast(unsigned short, __float2bfloat16(f));
}
// 2x f32 -> packed bf16x2 (compiler fuses the scalar-cast pair to v_cvt_pk_bf16_f32)
__device__ __forceinline__ unsigned bf16pk(float x, float y) {
    return (unsigned)bf16s(x) | ((unsigned)bf16s(y) << 16);
}
// sigmoid with z pre-scaled by log2(e): 1/(1 + 2^-z); v_exp neg-modifier free
__device__ __forceinline__ float sigm2(float z) {
    return __builtin_amdgcn_rcpf(1.0f + __builtin_amdgcn_exp2f(-z));
}
// tanh(c), c in linear domain: 2/(1+2^(c*CN2)) - 1
__device__ __forceinline__ float tanh2(float c) {
    return 2.0f * __builtin_amdgcn_rcpf(1.0f + __builtin_amdgcn_exp2f(c * CN2)) - 1.0f;
}

#define MFMA(A, B, C) __builtin_amdgcn_mfma_f32_16x16x32_bf16(A, B, C, 0, 0, 0)

// 8 waves, BT=8, one block/CU. Transposed MFMA, time-packed (col = batch + 8*dt).
// R23 = R21 revert (best: 139.4 us): exp2-domain bf16 weights (L2E folded;
// g-gate x2), HW cvt bf16 packs, xz ping-pong registers, in-place XV
// stage-then-reload, split XGEMM across phases, h hi-only bf16 planes.
__global__ __launch_bounds__(512, 1)
void lstm_mfma_kernel(const float* __restrict__ x,  const float* __restrict__ Wx,
                      const float* __restrict__ Wh, const float* __restrict__ bg,
                      const float* __restrict__ W1, const float* __restrict__ b1,
                      const float* __restrict__ W2, const float* __restrict__ b2,
                      const float* __restrict__ Wo, const float* __restrict__ bo,
                      float* __restrict__ out)
{
    const int tid = threadIdx.x;     // 0..511
    const int w   = tid >> 6;        // wave id 0..7
    const int L   = tid & 63;
    const int c16 = L & 15;          // B col: batch(0..7) + 8*dt / D col
    const int kg  = L >> 4;          // k-group AND unit-offset of D rows
    const int bb  = blockIdx.x * BT;
    const int jj  = (w << 2) + kg;   // hidden unit owned by this lane

    // A row m=c16 -> weight column; gate = c16&3; exp2-domain scale
    const int gcol = ((c16 & 3) << 5) + (w << 2) + (c16 >> 2);
    const float gsc = ((c16 & 3) == 2) ? (2.0f * L2E) : L2E;

    __shared__ __align__(16) unsigned short xh[4][16][XS];   // x hi-plane ring
    __shared__ __align__(16) unsigned short hh[2][16][HS];   // h hi-plane, parity
    __shared__ float Hd[3][BT][GS];

    // ---- register-resident weights (pure bf16, exp2-domain) ----
    bf16x8 whh_, wx0h, wx1h;
#pragma unroll
    for (int i = 0; i < 8; ++i) {
        wx0h[i] = (short)bf16s(Wx[(kg * 8 + i) * GQ + gcol] * gsc);
        wx1h[i] = (short)bf16s(Wx[(32 + kg * 8 + i) * GQ + gcol] * gsc);
        whh_[i] = (short)bf16s(Wh[(kg * 8 + i) * GQ + gcol] * gsc);
    }
    f32x4 biasC;
#pragma unroll
    for (int r = 0; r < 4; ++r)
        biasC[r] = bg[r * 32 + jj] * ((r == 2) ? (2.0f * L2E) : L2E);

    // ---- zero h planes (rows 8..15 stay zero forever) ----
    for (int i = tid; i < 2 * 16 * (HS / 2); i += 512)
        ((unsigned*)&hh[0][0][0])[i] = 0u;

    // staging map: row = batch(0..7) + 8*dt, feature pair; 1 u32 write per lane
    const int srow = tid >> 5;       // 0..15
    const int sfp  = tid & 31;       // feature pair
    const int sdt  = srow >> 3;      // dt 0/1
    const float* xsrc = x + (size_t)(bb + (srow & 7)) * S_ * F_ + 2 * sfp;
    const float* xs2  = xsrc + (size_t)sdt * F_;   // dt folded into base
    {
#pragma unroll
        for (int tt = 0; tt < 2; ++tt) {
            float2 v = *(const float2*)(xs2 + (size_t)(2 * tt) * F_);
            *(unsigned*)&xh[tt][srow][2 * sfp] = bf16pk(v.x, v.y);
        }
    }
    float2 xvA = *(const float2*)(xs2 + (size_t)4 * F_);   // slot 2
    float2 xvB = *(const float2*)(xs2 + (size_t)6 * F_);   // slot 3
    __syncthreads();

    // initial XGEMM (td=0) from slot 0 -> registers
    f32x4 xzA, xz1A, xzB, xz1B;
    {
        bf16x8 bxh0 = *(const bf16x8*)&xh[0][c16][kg * 8];
        bf16x8 bxh1 = *(const bf16x8*)&xh[0][c16][32 + kg * 8];
        f32x4 b0 = MFMA(wx0h, bxh0, biasC);
        xzA = MFMA(wx1h, bxh1, b0);
#pragma unroll
        for (int r = 0; r < 4; ++r) xz1A[r] = __shfl_xor(xzA[r], 8);
    }

    float cc = 0.0f;

#define DSTEP(TD, XZIN, XZ1IN, XZOUT, XZ1OUT, XV) {                            \
    const int td = (TD);                                                       \
    /* stage slot td+2 from XV, then reload XV in place (consumed td+2) */     \
    *(unsigned*)&xh[(td + 2) & 3][srow][2 * sfp] = bf16pk(XV.x, XV.y);         \
    int tl = td + 4; if (tl > 255) tl = 255;                                   \
    XV = *(const float2*)(xs2 + (size_t)(2 * tl) * F_);                        \
    const int s1 = (td + 1) & 3;                                               \
    /* phase 1: rec step 2td (h[2td-1] in plane 1) + XGEMM first half */       \
    bf16x8 bxh0 = *(const bf16x8*)&xh[s1][c16][kg * 8];                        \
    bf16x8 bhh1 = *(const bf16x8*)&hh[1][c16][kg * 8];                         \
    f32x4 part = MFMA(wx0h, bxh0, biasC);                                      \
    f32x4 z = MFMA(whh_, bhh1, XZIN);                                          \
    float iv = sigm2(z[0]), fv = sigm2(z[1]);                                  \
    float gv = 2.0f * sigm2(z[2]) - 1.0f, ov = sigm2(z[3]);                    \
    cc = fmaf(fv, cc, iv * gv);                                                \
    float hv = ov * tanh2(cc);                                                 \
    if (c16 < 8) hh[0][c16][jj] = bf16s(hv);                                   \
    __syncthreads();   /* A: h[2td] visible */                                 \
    /* phase 2: rec step 2td+1 + XGEMM second half */                          \
    bf16x8 bxh1 = *(const bf16x8*)&xh[s1][c16][32 + kg * 8];                   \
    bf16x8 bhh0 = *(const bf16x8*)&hh[0][c16][kg * 8];                         \
    XZOUT = MFMA(wx1h, bxh1, part);                                            \
    _Pragma("unroll")                                                          \
    for (int r = 0; r < 4; ++r) XZ1OUT[r] = __shfl_xor(XZOUT[r], 8);           \
    z = MFMA(whh_, bhh0, XZ1IN);                                               \
    iv = sigm2(z[0]); fv = sigm2(z[1]);                                        \
    gv = 2.0f * sigm2(z[2]) - 1.0f; ov = sigm2(z[3]);                          \
    cc = fmaf(fv, cc, iv * gv);                                                \
    hv = ov * tanh2(cc);                                                       \
    if (c16 < 8) {                                                             \
        hh[1][c16][jj] = bf16s(hv);                                            \
        if (td == 255) Hd[0][c16][jj] = hv;                                    \
    }                                                                          \
    __syncthreads();   /* B: h[2td+1] + slot td+2 visible */                   \
}

    for (int qd = 0; qd < 128; ++qd) {
        DSTEP(2 * qd,     xzA, xz1A, xzB, xz1B, xvA)
        DSTEP(2 * qd + 1, xzB, xz1B, xzA, xz1A, xvB)
    }
#undef DSTEP

    __syncthreads();

    // ---- MLP head: 32 -> 32 -> 16 -> 3, leaky_relu(0.01) ----
    if (tid < 256) {
        int rb = tid >> 5, n = tid & 31;
        float a = b1[n];
#pragma unroll
        for (int k = 0; k < 32; ++k) a = fmaf(Hd[0][rb][k], W1[k * 32 + n], a);
        a = (a > 0.0f) ? a : 0.01f * a;
        Hd[1][rb][n] = a;
    }
    __syncthreads();
    if (tid < 128) {
        int rb = tid >> 4, n = tid & 15;
        float a = b2[n];
#pragma unroll
        for (int k = 0; k < 32; ++k) a = fmaf(Hd[1][rb][k], W2[k * 16 + n], a);
        a = (a > 0.0f) ? a : 0.01f * a;
        Hd[2][rb][n] = a;
    }
    __syncthreads();
    if (tid < 24) {
        int rb = tid / 3, n = tid - rb * 3;
        float a = bo[n];
#pragma unroll
        for (int k = 0; k < 16; ++k) a = fmaf(Hd[2][rb][k], Wo[k * 3 + n], a);
        out[(size_t)(bb + rb) * 3 + n] = a;
    }
}

extern "C" void kernel_launch(void* const* d_in, const int* in_sizes, int n_in,
                              void* d_out, int out_size, void* d_ws, size_t ws_size,
                              hipStream_t stream) {
    const float* x  = (const float*)d_in[0];
    const float* Wx = (const float*)d_in[1];
    const float* Wh = (const float*)d_in[2];
    const float* bg = (const float*)d_in[3];
    const float* W1 = (const float*)d_in[4];
    const float* b1 = (const float*)d_in[5];
    const float* W2 = (const float*)d_in[6];
    const float* b2 = (const float*)d_in[7];
    const float* Wo = (const float*)d_in[8];
    const float* bo = (const float*)d_in[9];
    float* out = (float*)d_out;

    hipLaunchKernelGGL(lstm_mfma_kernel, dim3(NB), dim3(512), 0, stream,
                       x, Wx, Wh, bg, W1, b1, W2, b2, Wo, bo, out);
}